// Round 1
// baseline (4277.066 us; speedup 1.0000x reference)
//
#include <hip/hip_runtime.h>
#include <math.h>

typedef float2 c2;

#define S_IDX(i) ((i) ^ (((i) >> 5) & 15))

__device__ __forceinline__ c2 cmul(c2 a, c2 b){
  return make_float2(a.x*b.x - a.y*b.y, a.x*b.y + a.y*b.x);
}

__constant__ float c_foinv[5] = {3.0f, 6.3f, 13.23f, 27.783f, 58.3443f};

template<int SIGN>
__device__ __forceinline__ void make_tw(int t, c2* w){
#pragma unroll
  for (int k = 0; k < 5; ++k){
    const int s = 1 << (2*k);
    const float ang = (float)SIGN * 0.00613592315154256f * (float)(t & ~(s-1));
    sincosf(ang, &w[k].y, &w[k].x);
  }
}

// Radix-4 Stockham, N=1024, 256 threads, result ends in bufB, natural order.
template<int SIGN>
__device__ __forceinline__ void fft1024(c2* bufA, c2* bufB, int t, const c2* w){
  c2* cur = bufA; c2* oth = bufB;
#pragma unroll
  for (int k = 0; k < 5; ++k){
    const int s = 1 << (2*k);
    const int q = t & (s - 1);
    c2 a = cur[S_IDX(t)];
    c2 b = cur[S_IDX(t + 256)];
    c2 c = cur[S_IDX(t + 512)];
    c2 d = cur[S_IDX(t + 768)];
    c2 w1 = w[k];
    c2 w2 = cmul(w1, w1);
    c2 w3 = cmul(w2, w1);
    c2 apc = make_float2(a.x + c.x, a.y + c.y);
    c2 amc = make_float2(a.x - c.x, a.y - c.y);
    c2 bpd = make_float2(b.x + d.x, b.y + d.y);
    c2 bmd = make_float2(b.x - d.x, b.y - d.y);
    c2 y0 = make_float2(apc.x + bpd.x, apc.y + bpd.y);
    c2 e2 = make_float2(apc.x - bpd.x, apc.y - bpd.y);
    const float S4 = (float)SIGN;
    c2 u1 = make_float2(amc.x - S4*bmd.y, amc.y + S4*bmd.x);
    c2 u3 = make_float2(amc.x + S4*bmd.y, amc.y - S4*bmd.x);
    c2 y1 = cmul(u1, w1);
    c2 y2 = cmul(e2, w2);
    c2 y3 = cmul(u3, w3);
    const int bw = 4*t - 3*q;
    oth[S_IDX(bw)]       = y0;
    oth[S_IDX(bw + s)]   = y1;
    oth[S_IDX(bw + 2*s)] = y2;
    oth[S_IDX(bw + 3*s)] = y3;
    c2* tmp = cur; cur = oth; oth = tmp;
    __syncthreads();
  }
}

// Log-Gabor * lowpass * angular spread at DFT coords (r=q, c=a)
__device__ __forceinline__ float filt_eval(int q, int a, float xx,
                                           float cosA, float sinA, float foinv){
  const float yy = (float)(q < 512 ? q : q - 1024) * (1.0f/1024.0f);
  const float r2 = xx*xx + yy*yy;
  const bool isdc = (q == 0) && (a == 0);
  const float radius = isdc ? 1.0f : sqrtf(r2);
  // Butterworth lowpass (radius/0.45)^30
  const float tt = radius * (1.0f/0.45f);
  const float t2 = tt*tt, t4 = t2*t2, t8 = t4*t4, t16 = t8*t8;
  const float lp = 1.0f / (1.0f + t16*t8*t4*t2);
  // log-Gabor radial
  const float lnr = logf(radius * foinv);
  const float lg = expf(-lnr*lnr * 1.3989572f);   // 1/(2*ln(0.55)^2)
  // angular spread
  const float ir = 1.0f / radius;
  const float st = -yy * ir, ct = xx * ir;
  const float dsv = st*cosA - ct*sinA;
  const float dcv = ct*cosA + st*sinA;
  const float dth = fminf(fabsf(atan2f(dsv, dcv)) * 3.0f, 3.14159274f);
  const float spr = 0.5f * (cosf(dth) + 1.0f);
  const float f = lg * lp * spr;
  return isdc ? 0.0f : f;
}

__global__ __launch_bounds__(256) void k_fft_fwd_real(const float* __restrict__ in, c2* __restrict__ out){
  const int t = threadIdx.x;
  __shared__ c2 bufA[1024];
  __shared__ c2 bufB[1024];
  c2 w[5]; make_tw<-1>(t, w);
  for (int rr = 0; rr < 4; ++rr){
    const int row = blockIdx.x * 4 + rr;
    const float* src = in + (size_t)row * 1024;
    c2* dst = out + (size_t)row * 1024;
#pragma unroll
    for (int j = 0; j < 4; ++j){
      const int q = t + 256*j;
      bufA[S_IDX(q)] = make_float2(src[q], 0.0f);
    }
    __syncthreads();
    fft1024<-1>(bufA, bufB, t, w);
#pragma unroll
    for (int j = 0; j < 4; ++j){ const int q = t + 256*j; dst[q] = bufB[S_IDX(q)]; }
    __syncthreads();
  }
}

__global__ __launch_bounds__(256) void k_fft_fwd(const c2* __restrict__ in, c2* __restrict__ out){
  const int t = threadIdx.x;
  __shared__ c2 bufA[1024];
  __shared__ c2 bufB[1024];
  c2 w[5]; make_tw<-1>(t, w);
  for (int rr = 0; rr < 4; ++rr){
    const int row = blockIdx.x * 4 + rr;
    const c2* src = in + (size_t)row * 1024;
    c2* dst = out + (size_t)row * 1024;
#pragma unroll
    for (int j = 0; j < 4; ++j){ const int q = t + 256*j; bufA[S_IDX(q)] = src[q]; }
    __syncthreads();
    fft1024<-1>(bufA, bufB, t, w);
#pragma unroll
    for (int j = 0; j < 4; ++j){ const int q = t + 256*j; dst[q] = bufB[S_IDX(q)]; }
    __syncthreads();
  }
}

// Row-IDFT of (filt^T ⊙ F^T).  Row 'a' of F^T; filter evaluated at (r=q, c=a).
// Buffer slot = blockIdx.y; filter scale = sBase + blockIdx.y.
__global__ __launch_bounds__(256) void k_fft_inv_filter(const c2* __restrict__ F, c2* __restrict__ C,
                                                        float cosA, float sinA, int sBase){
  const int t = threadIdx.x;
  const int slot = blockIdx.y;
  const float foinv = c_foinv[sBase + slot];
  __shared__ c2 bufA[1024];
  __shared__ c2 bufB[1024];
  c2 w[5]; make_tw<1>(t, w);
  for (int rr = 0; rr < 4; ++rr){
    const int row = blockIdx.x * 4 + rr;      // a
    const c2* src = F + (size_t)row * 1024;
    c2* dst = C + (size_t)slot * 1048576 + (size_t)row * 1024;
    const float xx = (float)(row < 512 ? row : row - 1024) * (1.0f/1024.0f);
#pragma unroll
    for (int j = 0; j < 4; ++j){
      const int q = t + 256*j;
      const c2 v = src[q];
      const float f = filt_eval(q, row, xx, cosA, sinA, foinv);
      bufA[S_IDX(q)] = make_float2(v.x*f, v.y*f);
    }
    __syncthreads();
    fft1024<1>(bufA, bufB, t, w);
#pragma unroll
    for (int j = 0; j < 4; ++j){ const int q = t + 256*j; dst[q] = bufB[S_IDX(q)]; }
    __syncthreads();
  }
}

// In-place row-IDFT, batched over blockIdx.y slots.
__global__ __launch_bounds__(256) void k_fft_inv(c2* __restrict__ Z){
  const int t = threadIdx.x;
  c2* base = Z + (size_t)blockIdx.y * 1048576;
  __shared__ c2 bufA[1024];
  __shared__ c2 bufB[1024];
  c2 w[5]; make_tw<1>(t, w);
  for (int rr = 0; rr < 4; ++rr){
    const int row = blockIdx.x * 4 + rr;
    c2* p = base + (size_t)row * 1024;
#pragma unroll
    for (int j = 0; j < 4; ++j){ const int q = t + 256*j; bufA[S_IDX(q)] = p[q]; }
    __syncthreads();
    fft1024<1>(bufA, bufB, t, w);
#pragma unroll
    for (int j = 0; j < 4; ++j){ const int q = t + 256*j; p[q] = bufB[S_IDX(q)]; }
    __syncthreads();
  }
}

__global__ void k_transpose(const c2* __restrict__ in, c2* __restrict__ out){
  __shared__ c2 tile[32][33];
  const c2* src = in + (size_t)blockIdx.z * 1048576;
  c2* dst = out + (size_t)blockIdx.z * 1048576;
  const int bx = blockIdx.x * 32, by = blockIdx.y * 32;
  const int tx = threadIdx.x, ty = threadIdx.y;
#pragma unroll
  for (int j = 0; j < 32; j += 8)
    tile[ty + j][tx] = src[(size_t)(by + ty + j) * 1024 + bx + tx];
  __syncthreads();
#pragma unroll
  for (int j = 0; j < 32; j += 8)
    dst[(size_t)(bx + ty + j) * 1024 + by + tx] = tile[tx][ty + j];
}

__global__ __launch_bounds__(256) void k_hist_top(const c2* __restrict__ z0, unsigned* __restrict__ hist){
  const int base = blockIdx.x * 1024 + threadIdx.x;
#pragma unroll
  for (int j = 0; j < 4; ++j){
    const c2 v = z0[base + 256*j];
    const float an = sqrtf(v.x*v.x + v.y*v.y);
    const unsigned bits = __float_as_uint(an);
    atomicAdd(&hist[bits >> 16], 1u);
  }
}

__global__ __launch_bounds__(256) void k_scan_top(const unsigned* __restrict__ hist,
                                                  unsigned* __restrict__ sc,
                                                  unsigned* __restrict__ histB){
  __shared__ unsigned partial[256];
  __shared__ unsigned pfx[256];
  const int t = threadIdx.x;
  unsigned ssum = 0;
  for (int j = 0; j < 256; ++j) ssum += hist[t*256 + j];
  partial[t] = ssum;
  __syncthreads();
  unsigned p = 0;
  for (int u = 0; u < t; ++u) p += partial[u];
  pfx[t] = p;
  __syncthreads();
  for (int which = 0; which < 2; ++which){
    const unsigned R = 524287u + (unsigned)which;
    if (R >= pfx[t] && R - pfx[t] < partial[t]){
      unsigned cum = pfx[t];
      for (int j = 0; j < 256; ++j){
        const unsigned h = hist[t*256 + j];
        if (R - cum < h){ sc[which*2] = (unsigned)(t*256 + j); sc[which*2+1] = R - cum; break; }
        cum += h;
      }
    }
  }
  for (int j = t; j < 131072; j += 256) histB[j] = 0;
}

__global__ __launch_bounds__(256) void k_hist_low(const c2* __restrict__ z0,
                                                  const unsigned* __restrict__ sc,
                                                  unsigned* __restrict__ histB){
  const unsigned b0 = sc[0], b1 = sc[2];
  const int base = blockIdx.x * 1024 + threadIdx.x;
#pragma unroll
  for (int j = 0; j < 4; ++j){
    const c2 v = z0[base + 256*j];
    const float an = sqrtf(v.x*v.x + v.y*v.y);
    const unsigned bits = __float_as_uint(an);
    const unsigned top = bits >> 16;
    if (top == b0)      atomicAdd(&histB[bits & 0xFFFFu], 1u);
    else if (top == b1) atomicAdd(&histB[65536 + (bits & 0xFFFFu)], 1u);
  }
}

__global__ __launch_bounds__(256) void k_med_final(const unsigned* __restrict__ histB,
                                                   const unsigned* __restrict__ sc,
                                                   float* __restrict__ Tval){
  __shared__ unsigned partial[256];
  __shared__ unsigned pfx[256];
  __shared__ float vres[2];
  const int t = threadIdx.x;
  const unsigned b0 = sc[0], lr0 = sc[1], b1 = sc[2], lr1 = sc[3];
  for (int h = 0; h < 2; ++h){
    const unsigned* hh = histB + (h ? 65536 : 0);
    unsigned ssum = 0;
    for (int j = 0; j < 256; ++j) ssum += hh[t*256 + j];
    partial[t] = ssum;
    __syncthreads();
    unsigned p = 0;
    for (int u = 0; u < t; ++u) p += partial[u];
    pfx[t] = p;
    __syncthreads();
    for (int which = 0; which < 2; ++which){
      const bool inThis = (h == 0) ? (which == 0 || b1 == b0) : (which == 1 && b1 != b0);
      if (!inThis) continue;
      const unsigned R = which ? lr1 : lr0;
      if (R >= pfx[t] && R - pfx[t] < partial[t]){
        unsigned cum = pfx[t];
        for (int j = 0; j < 256; ++j){
          const unsigned hv = hh[t*256 + j];
          if (R - cum < hv){
            const unsigned bin = which ? b1 : b0;
            vres[which] = __uint_as_float((bin << 16) | (unsigned)(t*256 + j));
            break;
          }
          cum += hv;
        }
      }
    }
    __syncthreads();
  }
  if (t == 0){
    const float med = 0.5f * (vres[0] + vres[1]);
    const float tau = med / 1.17741001f;              // sqrt(ln 4)
    const float totalTau = tau * 1.8623464f;          // (1-(1/2.1)^5)/(1-1/2.1)
    const float T = totalTau * 1.25331414f + 2.0f * totalTau * 0.65513638f;
    *Tval = T;
  }
}

__global__ __launch_bounds__(256) void k_pix(const c2* __restrict__ Z, const float* __restrict__ Tp,
                                             float cA, float sA,
                                             float* __restrict__ ax2, float* __restrict__ ay2,
                                             float* __restrict__ axy, int first){
  const int i = blockIdx.x * 256 + threadIdx.x;
  const float T = *Tp;
  float E[5], O[5];
  float sumE = 0.f, sumO = 0.f, sumAn = 0.f, maxAn = 0.f;
#pragma unroll
  for (int s = 0; s < 5; ++s){
    const c2 z = Z[(size_t)s * 1048576 + i];
    O[s] = z.x; E[s] = z.y;
    const float an = sqrtf(z.x*z.x + z.y*z.y);
    sumE += E[s]; sumO += O[s]; sumAn += an; maxAn = fmaxf(maxAn, an);
  }
  const float XE = sqrtf(sumE*sumE + sumO*sumO) + 1e-4f;
  const float ME = sumE / XE, MO = sumO / XE;
  float energy = 0.f;
#pragma unroll
  for (int s = 0; s < 5; ++s)
    energy += E[s]*ME + O[s]*MO - fabsf(E[s]*MO - O[s]*ME);
  energy = fmaxf(energy - T, 0.f);
  const float width = (sumAn / (maxAn + 1e-4f) - 1.0f) * 0.25f;
  const float weight = 1.0f / (1.0f + expf((0.5f - width) * 10.0f));
  const float PC = weight * energy / sumAn;
  const float cx = PC * cA, cy = PC * sA;
  if (first){ ax2[i] = cx*cx; ay2[i] = cy*cy; axy[i] = cx*cy; }
  else      { ax2[i] += cx*cx; ay2[i] += cy*cy; axy[i] += cx*cy; }
}

__global__ __launch_bounds__(256) void k_final(const float* __restrict__ ax2, const float* __restrict__ ay2,
                                               const float* __restrict__ axy, float* __restrict__ out){
  const int i = blockIdx.x * 256 + threadIdx.x;
  const float cx2 = ax2[i] / 3.0f;
  const float cy2 = ay2[i] / 3.0f;
  const float cxy = 4.0f * axy[i] / 6.0f;
  const float dnm = sqrtf(cxy*cxy + (cx2 - cy2)*(cx2 - cy2)) + 1e-4f;
  const float ss = cy2 + cx2;
  out[i] = (ss + dnm) / 2.0f;
  out[1048576 + i] = (ss - dnm) / 2.0f;
}

extern "C" void kernel_launch(void* const* d_in, const int* in_sizes, int n_in,
                              void* d_out, int out_size, void* d_ws, size_t ws_size,
                              hipStream_t stream){
  (void)in_sizes; (void)n_in; (void)out_size;
  const float* img = (const float*)d_in[0];
  float* out = (float*)d_out;
  char* w = (char*)d_ws;

  c2* F        = (c2*)(w);                      // 8 MB
  c2* Z        = (c2*)(w + 8388608);            // 5 x 8 MB
  float* ax2   = (float*)(w + 50331648);        // 4 MB
  float* ay2   = ax2 + 1048576;
  float* axy   = ay2 + 1048576;
  unsigned* histA = (unsigned*)(w + 62914560);  // 256 KB
  unsigned* histB = (unsigned*)(w + 63176704);  // 512 KB
  unsigned* sc    = (unsigned*)(w + 63700992);  // 64 B
  float* Tval     = (float*)(w + 63701056);
  c2* C        = (c2*)(w + 67108864);           // 8 MB (medium) or 40 MB (big)
  const bool big = (ws_size >= (size_t)109051904);

  const dim3 th(256);
  // forward: rows-FFT(img) -> Z0 ; transpose -> C0 ; rows-FFT -> F (= F^T)
  k_fft_fwd_real<<<dim3(256), th, 0, stream>>>(img, Z);
  k_transpose<<<dim3(32,32,1), dim3(32,8), 0, stream>>>(Z, C);
  k_fft_fwd<<<dim3(256), th, 0, stream>>>(C, F);

  for (int o = 0; o < 6; ++o){
    const float a32 = (float)o * (float)(M_PI/6.0);
    const float cA = cosf(a32), sA = sinf(a32);
    if (big){
      k_fft_inv_filter<<<dim3(256,5), th, 0, stream>>>(F, C, cA, sA, 0);
      k_transpose<<<dim3(32,32,5), dim3(32,8), 0, stream>>>(C, Z);
    } else {
      for (int s = 0; s < 5; ++s){
        k_fft_inv_filter<<<dim3(256,1), th, 0, stream>>>(F, C, cA, sA, s);
        k_transpose<<<dim3(32,32,1), dim3(32,8), 0, stream>>>(C, Z + (size_t)s*1048576);
      }
    }
    k_fft_inv<<<dim3(256,5), th, 0, stream>>>(Z);

    hipMemsetAsync(histA, 0, 262144, stream);
    k_hist_top<<<dim3(1024), th, 0, stream>>>(Z, histA);
    k_scan_top<<<dim3(1), th, 0, stream>>>(histA, sc, histB);
    k_hist_low<<<dim3(1024), th, 0, stream>>>(Z, sc, histB);
    k_med_final<<<dim3(1), th, 0, stream>>>(histB, sc, Tval);

    k_pix<<<dim3(4096), th, 0, stream>>>(Z, Tval, cA, sA, ax2, ay2, axy, (o == 0) ? 1 : 0);
  }
  k_final<<<dim3(4096), th, 0, stream>>>(ax2, ay2, axy, out);
}

// Round 2
// 932.756 us; speedup vs baseline: 4.5854x; 4.5854x over previous
//
#include <hip/hip_runtime.h>
#include <math.h>

typedef float2 c2;

#define S_IDX(i) ((i) ^ (((i) >> 5) & 15))

__device__ __forceinline__ c2 cmul(c2 a, c2 b){
  return make_float2(a.x*b.x - a.y*b.y, a.x*b.y + a.y*b.x);
}

__constant__ float c_foinv[5] = {3.0f, 6.3f, 13.23f, 27.783f, 58.3443f};

template<int SIGN>
__device__ __forceinline__ void make_tw(int t, c2* w){
#pragma unroll
  for (int k = 0; k < 5; ++k){
    const int s = 1 << (2*k);
    const float ang = (float)SIGN * 0.00613592315154256f * (float)(t & ~(s-1));
    sincosf(ang, &w[k].y, &w[k].x);
  }
}

// Radix-4 Stockham, N=1024, 256 threads, result ends in bufB, natural order.
template<int SIGN>
__device__ __forceinline__ void fft1024(c2* bufA, c2* bufB, int t, const c2* w){
  c2* cur = bufA; c2* oth = bufB;
#pragma unroll
  for (int k = 0; k < 5; ++k){
    const int s = 1 << (2*k);
    const int q = t & (s - 1);
    c2 a = cur[S_IDX(t)];
    c2 b = cur[S_IDX(t + 256)];
    c2 c = cur[S_IDX(t + 512)];
    c2 d = cur[S_IDX(t + 768)];
    c2 w1 = w[k];
    c2 w2 = cmul(w1, w1);
    c2 w3 = cmul(w2, w1);
    c2 apc = make_float2(a.x + c.x, a.y + c.y);
    c2 amc = make_float2(a.x - c.x, a.y - c.y);
    c2 bpd = make_float2(b.x + d.x, b.y + d.y);
    c2 bmd = make_float2(b.x - d.x, b.y - d.y);
    c2 y0 = make_float2(apc.x + bpd.x, apc.y + bpd.y);
    c2 e2 = make_float2(apc.x - bpd.x, apc.y - bpd.y);
    const float S4 = (float)SIGN;
    c2 u1 = make_float2(amc.x - S4*bmd.y, amc.y + S4*bmd.x);
    c2 u3 = make_float2(amc.x + S4*bmd.y, amc.y - S4*bmd.x);
    c2 y1 = cmul(u1, w1);
    c2 y2 = cmul(e2, w2);
    c2 y3 = cmul(u3, w3);
    const int bw = 4*t - 3*q;
    oth[S_IDX(bw)]       = y0;
    oth[S_IDX(bw + s)]   = y1;
    oth[S_IDX(bw + 2*s)] = y2;
    oth[S_IDX(bw + 3*s)] = y3;
    c2* tmp = cur; cur = oth; oth = tmp;
    __syncthreads();
  }
}

// Log-Gabor * lowpass * angular spread at DFT coords (r=q, c=a)
__device__ __forceinline__ float filt_eval(int q, int a, float xx,
                                           float cosA, float sinA, float foinv){
  const float yy = (float)(q < 512 ? q : q - 1024) * (1.0f/1024.0f);
  const float r2 = xx*xx + yy*yy;
  const bool isdc = (q == 0) && (a == 0);
  const float radius = isdc ? 1.0f : sqrtf(r2);
  // Butterworth lowpass (radius/0.45)^30
  const float tt = radius * (1.0f/0.45f);
  const float t2 = tt*tt, t4 = t2*t2, t8 = t4*t4, t16 = t8*t8;
  const float lp = 1.0f / (1.0f + t16*t8*t4*t2);
  // log-Gabor radial
  const float lnr = logf(radius * foinv);
  const float lg = expf(-lnr*lnr * 1.3989572f);   // 1/(2*ln(0.55)^2)
  // angular spread
  const float ir = 1.0f / radius;
  const float st = -yy * ir, ct = xx * ir;
  const float dsv = st*cosA - ct*sinA;
  const float dcv = ct*cosA + st*sinA;
  const float dth = fminf(fabsf(atan2f(dsv, dcv)) * 3.0f, 3.14159274f);
  const float spr = 0.5f * (cosf(dth) + 1.0f);
  const float f = lg * lp * spr;
  return isdc ? 0.0f : f;
}

__global__ __launch_bounds__(256) void k_fft_fwd_real(const float* __restrict__ in, c2* __restrict__ out){
  const int t = threadIdx.x;
  __shared__ c2 bufA[1024];
  __shared__ c2 bufB[1024];
  c2 w[5]; make_tw<-1>(t, w);
  for (int rr = 0; rr < 4; ++rr){
    const int row = blockIdx.x * 4 + rr;
    const float* src = in + (size_t)row * 1024;
    c2* dst = out + (size_t)row * 1024;
#pragma unroll
    for (int j = 0; j < 4; ++j){
      const int q = t + 256*j;
      bufA[S_IDX(q)] = make_float2(src[q], 0.0f);
    }
    __syncthreads();
    fft1024<-1>(bufA, bufB, t, w);
#pragma unroll
    for (int j = 0; j < 4; ++j){ const int q = t + 256*j; dst[q] = bufB[S_IDX(q)]; }
    __syncthreads();
  }
}

__global__ __launch_bounds__(256) void k_fft_fwd(const c2* __restrict__ in, c2* __restrict__ out){
  const int t = threadIdx.x;
  __shared__ c2 bufA[1024];
  __shared__ c2 bufB[1024];
  c2 w[5]; make_tw<-1>(t, w);
  for (int rr = 0; rr < 4; ++rr){
    const int row = blockIdx.x * 4 + rr;
    const c2* src = in + (size_t)row * 1024;
    c2* dst = out + (size_t)row * 1024;
#pragma unroll
    for (int j = 0; j < 4; ++j){ const int q = t + 256*j; bufA[S_IDX(q)] = src[q]; }
    __syncthreads();
    fft1024<-1>(bufA, bufB, t, w);
#pragma unroll
    for (int j = 0; j < 4; ++j){ const int q = t + 256*j; dst[q] = bufB[S_IDX(q)]; }
    __syncthreads();
  }
}

// Row-IDFT of (filt^T ⊙ F^T).  Row 'a' of F^T; filter evaluated at (r=q, c=a).
__global__ __launch_bounds__(256) void k_fft_inv_filter(const c2* __restrict__ F, c2* __restrict__ C,
                                                        float cosA, float sinA, int sBase){
  const int t = threadIdx.x;
  const int slot = blockIdx.y;
  const float foinv = c_foinv[sBase + slot];
  __shared__ c2 bufA[1024];
  __shared__ c2 bufB[1024];
  c2 w[5]; make_tw<1>(t, w);
  for (int rr = 0; rr < 4; ++rr){
    const int row = blockIdx.x * 4 + rr;      // a
    const c2* src = F + (size_t)row * 1024;
    c2* dst = C + (size_t)slot * 1048576 + (size_t)row * 1024;
    const float xx = (float)(row < 512 ? row : row - 1024) * (1.0f/1024.0f);
#pragma unroll
    for (int j = 0; j < 4; ++j){
      const int q = t + 256*j;
      const c2 v = src[q];
      const float f = filt_eval(q, row, xx, cosA, sinA, foinv);
      bufA[S_IDX(q)] = make_float2(v.x*f, v.y*f);
    }
    __syncthreads();
    fft1024<1>(bufA, bufB, t, w);
#pragma unroll
    for (int j = 0; j < 4; ++j){ const int q = t + 256*j; dst[q] = bufB[S_IDX(q)]; }
    __syncthreads();
  }
}

// In-place row-IDFT, batched over blockIdx.y slots.
__global__ __launch_bounds__(256) void k_fft_inv(c2* __restrict__ Z){
  const int t = threadIdx.x;
  c2* base = Z + (size_t)blockIdx.y * 1048576;
  __shared__ c2 bufA[1024];
  __shared__ c2 bufB[1024];
  c2 w[5]; make_tw<1>(t, w);
  for (int rr = 0; rr < 4; ++rr){
    const int row = blockIdx.x * 4 + rr;
    c2* p = base + (size_t)row * 1024;
#pragma unroll
    for (int j = 0; j < 4; ++j){ const int q = t + 256*j; bufA[S_IDX(q)] = p[q]; }
    __syncthreads();
    fft1024<1>(bufA, bufB, t, w);
#pragma unroll
    for (int j = 0; j < 4; ++j){ const int q = t + 256*j; p[q] = bufB[S_IDX(q)]; }
    __syncthreads();
  }
}

__global__ void k_transpose(const c2* __restrict__ in, c2* __restrict__ out){
  __shared__ c2 tile[32][33];
  const c2* src = in + (size_t)blockIdx.z * 1048576;
  c2* dst = out + (size_t)blockIdx.z * 1048576;
  const int bx = blockIdx.x * 32, by = blockIdx.y * 32;
  const int tx = threadIdx.x, ty = threadIdx.y;
#pragma unroll
  for (int j = 0; j < 32; j += 8)
    tile[ty + j][tx] = src[(size_t)(by + ty + j) * 1024 + bx + tx];
  __syncthreads();
#pragma unroll
  for (int j = 0; j < 32; j += 8)
    dst[(size_t)(bx + ty + j) * 1024 + by + tx] = tile[tx][ty + j];
}

// ---------------- exact median via 3-level radix select (12/12/8 bits) ----------
// Amplitudes are non-negative floats -> bit pattern is monotone in value.

__device__ __forceinline__ unsigned amp_bits(const c2 v){
  return __float_as_uint(sqrtf(v.x*v.x + v.y*v.y));
}

// Pass 1: histogram of top 12 bits; per-wave LDS privatization.
__global__ __launch_bounds__(256) void k_med_p1(const c2* __restrict__ z0, unsigned* __restrict__ g1){
  __shared__ unsigned h[4][4096];
  const int t = threadIdx.x;
  const int wv = t >> 6;
  for (int j = t; j < 4*4096; j += 256) ((unsigned*)h)[j] = 0;
  __syncthreads();
  const int base = blockIdx.x * 16384;
  for (int it = 0; it < 64; ++it){
    const unsigned bits = amp_bits(z0[base + it*256 + t]);
    atomicAdd(&h[wv][bits >> 20], 1u);
  }
  __syncthreads();
  for (int j = t; j < 4096; j += 256){
    const unsigned s = h[0][j] + h[1][j] + h[2][j] + h[3][j];
    if (s) atomicAdd(&g1[j], s);
  }
}

// Select top-12 bin for ranks 524287/524288; zero g2.
__global__ __launch_bounds__(256) void k_sel1(const unsigned* __restrict__ g1,
                                              unsigned* __restrict__ sc1,
                                              unsigned* __restrict__ g2){
  __shared__ unsigned partial[256];
  const int t = threadIdx.x;
  unsigned loc[16]; unsigned s = 0;
#pragma unroll
  for (int j = 0; j < 16; ++j){ loc[j] = g1[t*16 + j]; s += loc[j]; }
  partial[t] = s;
  __syncthreads();
  unsigned p = 0;
  for (int u = 0; u < t; ++u) p += partial[u];
  for (int which = 0; which < 2; ++which){
    const unsigned R = 524287u + (unsigned)which;
    if (R >= p && R - p < s){
      unsigned cum = p;
      for (int j = 0; j < 16; ++j){
        if (R - cum < loc[j]){ sc1[which*2] = (unsigned)(t*16 + j); sc1[which*2+1] = R - cum; break; }
        cum += loc[j];
      }
    }
  }
  for (int j = t; j < 8192; j += 256) g2[j] = 0;
}

// Pass 2: among elements matching top-12 bin, histogram of bits 19..8.
__global__ __launch_bounds__(256) void k_med_p2(const c2* __restrict__ z0,
                                                const unsigned* __restrict__ sc1,
                                                unsigned* __restrict__ g2){
  __shared__ unsigned h[2][4096];
  const int t = threadIdx.x;
  for (int j = t; j < 8192; j += 256) ((unsigned*)h)[j] = 0;
  __syncthreads();
  const unsigned b0 = sc1[0], b1 = sc1[2];
  const int base = blockIdx.x * 16384;
  for (int it = 0; it < 64; ++it){
    const unsigned bits = amp_bits(z0[base + it*256 + t]);
    const unsigned top = bits >> 20;
    const unsigned mid = (bits >> 8) & 4095u;
    if (top == b0)              atomicAdd(&h[0][mid], 1u);
    else if (top == b1)         atomicAdd(&h[1][mid], 1u);
  }
  __syncthreads();
  for (int j = t; j < 4096; j += 256){
    if (h[0][j]) atomicAdd(&g2[j], h[0][j]);
    if (h[1][j]) atomicAdd(&g2[4096 + j], h[1][j]);
  }
}

__global__ __launch_bounds__(256) void k_sel2(const unsigned* __restrict__ g2,
                                              const unsigned* __restrict__ sc1,
                                              unsigned* __restrict__ sc2,
                                              unsigned* __restrict__ g3){
  __shared__ unsigned partial[256];
  const int t = threadIdx.x;
  const unsigned b0 = sc1[0], lr0 = sc1[1], b1 = sc1[2], lr1 = sc1[3];
  for (int which = 0; which < 2; ++which){
    const unsigned* hh = g2 + ((which == 1 && b1 != b0) ? 4096 : 0);
    const unsigned R = which ? lr1 : lr0;
    unsigned loc[16]; unsigned s = 0;
#pragma unroll
    for (int j = 0; j < 16; ++j){ loc[j] = hh[t*16 + j]; s += loc[j]; }
    partial[t] = s;
    __syncthreads();
    unsigned p = 0;
    for (int u = 0; u < t; ++u) p += partial[u];
    if (R >= p && R - p < s){
      unsigned cum = p;
      for (int j = 0; j < 16; ++j){
        if (R - cum < loc[j]){ sc2[which*2] = (unsigned)(t*16 + j); sc2[which*2+1] = R - cum; break; }
        cum += loc[j];
      }
    }
    __syncthreads();
  }
  for (int j = t; j < 512; j += 256) g3[j] = 0;
}

// Pass 3: among elements matching top-24 bits, histogram of low 8 bits.
__global__ __launch_bounds__(256) void k_med_p3(const c2* __restrict__ z0,
                                                const unsigned* __restrict__ sc1,
                                                const unsigned* __restrict__ sc2,
                                                unsigned* __restrict__ g3){
  __shared__ unsigned h[2][256];
  const int t = threadIdx.x;
  h[0][t] = 0; h[1][t] = 0;
  __syncthreads();
  const unsigned k0 = (sc1[0] << 12) | sc2[0];
  const unsigned k1 = (sc1[2] << 12) | sc2[2];
  const int base = blockIdx.x * 16384;
  for (int it = 0; it < 64; ++it){
    const unsigned bits = amp_bits(z0[base + it*256 + t]);
    const unsigned key = bits >> 8;
    if (key == k0)       atomicAdd(&h[0][bits & 255u], 1u);
    else if (key == k1)  atomicAdd(&h[1][bits & 255u], 1u);
  }
  __syncthreads();
  if (h[0][t]) atomicAdd(&g3[t], h[0][t]);
  if (h[1][t]) atomicAdd(&g3[256 + t], h[1][t]);
}

__global__ __launch_bounds__(256) void k_sel3(const unsigned* __restrict__ g3,
                                              const unsigned* __restrict__ sc1,
                                              const unsigned* __restrict__ sc2,
                                              float* __restrict__ Tval){
  __shared__ unsigned partial[256];
  __shared__ float vres[2];
  const int t = threadIdx.x;
  const unsigned k0 = (sc1[0] << 12) | sc2[0];
  const unsigned k1 = (sc1[2] << 12) | sc2[2];
  for (int which = 0; which < 2; ++which){
    const unsigned* hh = g3 + ((which == 1 && k1 != k0) ? 256 : 0);
    const unsigned R = which ? sc2[3] : sc2[1];
    partial[t] = hh[t];
    __syncthreads();
    unsigned p = 0;
    for (int u = 0; u < t; ++u) p += partial[u];
    if (R >= p && R - p < partial[t]){
      const unsigned key = which ? k1 : k0;
      vres[which] = __uint_as_float((key << 8) | (unsigned)t);
    }
    __syncthreads();
  }
  if (t == 0){
    const float med = 0.5f * (vres[0] + vres[1]);
    const float tau = med / 1.17741001f;              // sqrt(ln 4)
    const float totalTau = tau * 1.8623464f;          // (1-(1/2.1)^5)/(1-1/2.1)
    const float T = totalTau * 1.25331414f + 2.0f * totalTau * 0.65513638f;
    *Tval = T;
  }
}

// ---------------------------------------------------------------------------

__global__ __launch_bounds__(256) void k_pix(const c2* __restrict__ Z, const float* __restrict__ Tp,
                                             float cA, float sA,
                                             float* __restrict__ ax2, float* __restrict__ ay2,
                                             float* __restrict__ axy, int first){
  const int i = blockIdx.x * 256 + threadIdx.x;
  const float T = *Tp;
  float E[5], O[5];
  float sumE = 0.f, sumO = 0.f, sumAn = 0.f, maxAn = 0.f;
#pragma unroll
  for (int s = 0; s < 5; ++s){
    const c2 z = Z[(size_t)s * 1048576 + i];
    O[s] = z.x; E[s] = z.y;
    const float an = sqrtf(z.x*z.x + z.y*z.y);
    sumE += E[s]; sumO += O[s]; sumAn += an; maxAn = fmaxf(maxAn, an);
  }
  const float XE = sqrtf(sumE*sumE + sumO*sumO) + 1e-4f;
  const float ME = sumE / XE, MO = sumO / XE;
  float energy = 0.f;
#pragma unroll
  for (int s = 0; s < 5; ++s)
    energy += E[s]*ME + O[s]*MO - fabsf(E[s]*MO - O[s]*ME);
  energy = fmaxf(energy - T, 0.f);
  const float width = (sumAn / (maxAn + 1e-4f) - 1.0f) * 0.25f;
  const float weight = 1.0f / (1.0f + expf((0.5f - width) * 10.0f));
  const float PC = weight * energy / sumAn;
  const float cx = PC * cA, cy = PC * sA;
  if (first){ ax2[i] = cx*cx; ay2[i] = cy*cy; axy[i] = cx*cy; }
  else      { ax2[i] += cx*cx; ay2[i] += cy*cy; axy[i] += cx*cy; }
}

__global__ __launch_bounds__(256) void k_final(const float* __restrict__ ax2, const float* __restrict__ ay2,
                                               const float* __restrict__ axy, float* __restrict__ out){
  const int i = blockIdx.x * 256 + threadIdx.x;
  const float cx2 = ax2[i] / 3.0f;
  const float cy2 = ay2[i] / 3.0f;
  const float cxy = 4.0f * axy[i] / 6.0f;
  const float dnm = sqrtf(cxy*cxy + (cx2 - cy2)*(cx2 - cy2)) + 1e-4f;
  const float ss = cy2 + cx2;
  out[i] = (ss + dnm) / 2.0f;
  out[1048576 + i] = (ss - dnm) / 2.0f;
}

extern "C" void kernel_launch(void* const* d_in, const int* in_sizes, int n_in,
                              void* d_out, int out_size, void* d_ws, size_t ws_size,
                              hipStream_t stream){
  (void)in_sizes; (void)n_in; (void)out_size;
  const float* img = (const float*)d_in[0];
  float* out = (float*)d_out;
  char* w = (char*)d_ws;

  c2* F        = (c2*)(w);                      // 8 MB
  c2* Z        = (c2*)(w + 8388608);            // 5 x 8 MB
  float* ax2   = (float*)(w + 50331648);        // 3 x 4 MB
  float* ay2   = ax2 + 1048576;
  float* axy   = ay2 + 1048576;
  unsigned* g1   = (unsigned*)(w + 62914560);   // 16 KB
  unsigned* g2   = (unsigned*)(w + 62930944);   // 32 KB
  unsigned* g3   = (unsigned*)(w + 62963712);   // 2 KB
  unsigned* sc1  = (unsigned*)(w + 62965760);
  unsigned* sc2  = (unsigned*)(w + 62965824);
  float* Tval    = (float*)(w + 62965888);
  c2* C        = (c2*)(w + 67108864);           // 8 MB (medium) or 40 MB (big)
  const bool big = (ws_size >= (size_t)109051904);

  const dim3 th(256);
  // forward: rows-FFT(img) -> Z0 ; transpose -> C0 ; rows-FFT -> F (= F^T)
  k_fft_fwd_real<<<dim3(256), th, 0, stream>>>(img, Z);
  k_transpose<<<dim3(32,32,1), dim3(32,8), 0, stream>>>(Z, C);
  k_fft_fwd<<<dim3(256), th, 0, stream>>>(C, F);

  for (int o = 0; o < 6; ++o){
    const float a32 = (float)o * (float)(M_PI/6.0);
    const float cA = cosf(a32), sA = sinf(a32);
    if (big){
      k_fft_inv_filter<<<dim3(256,5), th, 0, stream>>>(F, C, cA, sA, 0);
      k_transpose<<<dim3(32,32,5), dim3(32,8), 0, stream>>>(C, Z);
    } else {
      for (int s = 0; s < 5; ++s){
        k_fft_inv_filter<<<dim3(256,1), th, 0, stream>>>(F, C, cA, sA, s);
        k_transpose<<<dim3(32,32,1), dim3(32,8), 0, stream>>>(C, Z + (size_t)s*1048576);
      }
    }
    k_fft_inv<<<dim3(256,5), th, 0, stream>>>(Z);

    // exact median of |Z slot 0| via 3-level radix select
    hipMemsetAsync(g1, 0, 16384, stream);
    k_med_p1<<<dim3(64), th, 0, stream>>>(Z, g1);
    k_sel1<<<dim3(1), th, 0, stream>>>(g1, sc1, g2);
    k_med_p2<<<dim3(64), th, 0, stream>>>(Z, sc1, g2);
    k_sel2<<<dim3(1), th, 0, stream>>>(g2, sc1, sc2, g3);
    k_med_p3<<<dim3(64), th, 0, stream>>>(Z, sc1, sc2, g3);
    k_sel3<<<dim3(1), th, 0, stream>>>(g3, sc1, sc2, Tval);

    k_pix<<<dim3(4096), th, 0, stream>>>(Z, Tval, cA, sA, ax2, ay2, axy, (o == 0) ? 1 : 0);
  }
  k_final<<<dim3(4096), th, 0, stream>>>(ax2, ay2, axy, out);
}

// Round 4
// 485.981 us; speedup vs baseline: 8.8009x; 1.9193x over previous
//
#include <hip/hip_runtime.h>
#include <math.h>

typedef float2 c2;

#define S_IDX(i) ((i) ^ (((i) >> 5) & 15))

__device__ __forceinline__ c2 cmul(c2 a, c2 b){
  return make_float2(a.x*b.x - a.y*b.y, a.x*b.y + a.y*b.x);
}

__constant__ float c_foinv[5] = {3.0f, 6.3f, 13.23f, 27.783f, 58.3443f};
__constant__ float c_cosA[6] = {1.0f, 0.8660254038f, 0.5f, 6.123233996e-17f, -0.5f, -0.8660254038f};
__constant__ float c_sinA[6] = {0.0f, 0.5f, 0.8660254038f, 1.0f, 0.8660254038f, 0.5f};

template<int SIGN>
__device__ __forceinline__ void make_tw(int t, c2* w){
#pragma unroll
  for (int k = 0; k < 5; ++k){
    const int s = 1 << (2*k);
    const float ang = (float)SIGN * 0.00613592315154256f * (float)(t & ~(s-1));
    sincosf(ang, &w[k].y, &w[k].x);
  }
}

// Radix-4 Stockham, N=1024, 256 threads, result ends in bufB, natural order.
template<int SIGN>
__device__ __forceinline__ void fft1024(c2* bufA, c2* bufB, int t, const c2* w){
  c2* cur = bufA; c2* oth = bufB;
#pragma unroll
  for (int k = 0; k < 5; ++k){
    const int s = 1 << (2*k);
    const int q = t & (s - 1);
    c2 a = cur[S_IDX(t)];
    c2 b = cur[S_IDX(t + 256)];
    c2 c = cur[S_IDX(t + 512)];
    c2 d = cur[S_IDX(t + 768)];
    c2 w1 = w[k];
    c2 w2 = cmul(w1, w1);
    c2 w3 = cmul(w2, w1);
    c2 apc = make_float2(a.x + c.x, a.y + c.y);
    c2 amc = make_float2(a.x - c.x, a.y - c.y);
    c2 bpd = make_float2(b.x + d.x, b.y + d.y);
    c2 bmd = make_float2(b.x - d.x, b.y - d.y);
    c2 y0 = make_float2(apc.x + bpd.x, apc.y + bpd.y);
    c2 e2 = make_float2(apc.x - bpd.x, apc.y - bpd.y);
    const float S4 = (float)SIGN;
    c2 u1 = make_float2(amc.x - S4*bmd.y, amc.y + S4*bmd.x);
    c2 u3 = make_float2(amc.x + S4*bmd.y, amc.y - S4*bmd.x);
    c2 y1 = cmul(u1, w1);
    c2 y2 = cmul(e2, w2);
    c2 y3 = cmul(u3, w3);
    const int bw = 4*t - 3*q;
    oth[S_IDX(bw)]       = y0;
    oth[S_IDX(bw + s)]   = y1;
    oth[S_IDX(bw + 2*s)] = y2;
    oth[S_IDX(bw + 3*s)] = y3;
    c2* tmp = cur; cur = oth; oth = tmp;
    __syncthreads();
  }
}

// Log-Gabor * lowpass * angular spread at DFT coords (r=q, c=a)
__device__ __forceinline__ float filt_eval(int q, int a, float xx,
                                           float cosA, float sinA, float foinv){
  const float yy = (float)(q < 512 ? q : q - 1024) * (1.0f/1024.0f);
  const float r2 = xx*xx + yy*yy;
  const bool isdc = (q == 0) && (a == 0);
  const float radius = isdc ? 1.0f : sqrtf(r2);
  const float tt = radius * (1.0f/0.45f);
  const float t2 = tt*tt, t4 = t2*t2, t8 = t4*t4, t16 = t8*t8;
  const float lp = 1.0f / (1.0f + t16*t8*t4*t2);
  const float lnr = logf(radius * foinv);
  const float lg = expf(-lnr*lnr * 1.3989572f);   // 1/(2*ln(0.55)^2)
  const float ir = 1.0f / radius;
  const float st = -yy * ir, ct = xx * ir;
  const float dsv = st*cosA - ct*sinA;
  const float dcv = ct*cosA + st*sinA;
  const float dth = fminf(fabsf(atan2f(dsv, dcv)) * 3.0f, 3.14159274f);
  const float spr = 0.5f * (cosf(dth) + 1.0f);
  const float f = lg * lp * spr;
  return isdc ? 0.0f : f;
}

__global__ __launch_bounds__(256) void k_fft_fwd_real(const float* __restrict__ in, c2* __restrict__ out){
  const int t = threadIdx.x;
  __shared__ c2 bufA[1024];
  __shared__ c2 bufB[1024];
  c2 w[5]; make_tw<-1>(t, w);
  for (int rr = 0; rr < 4; ++rr){
    const int row = blockIdx.x * 4 + rr;
    const float* src = in + (size_t)row * 1024;
    c2* dst = out + (size_t)row * 1024;
#pragma unroll
    for (int j = 0; j < 4; ++j){
      const int q = t + 256*j;
      bufA[S_IDX(q)] = make_float2(src[q], 0.0f);
    }
    __syncthreads();
    fft1024<-1>(bufA, bufB, t, w);
#pragma unroll
    for (int j = 0; j < 4; ++j){ const int q = t + 256*j; dst[q] = bufB[S_IDX(q)]; }
    __syncthreads();
  }
}

// In-place row-FFT (forward), slot = blockIdx.y
__global__ __launch_bounds__(256) void k_fft_fwd_ip(c2* __restrict__ Z){
  const int t = threadIdx.x;
  c2* base = Z + (size_t)blockIdx.y * 1048576;
  __shared__ c2 bufA[1024];
  __shared__ c2 bufB[1024];
  c2 w[5]; make_tw<-1>(t, w);
  for (int rr = 0; rr < 4; ++rr){
    const int row = blockIdx.x * 4 + rr;
    c2* p = base + (size_t)row * 1024;
#pragma unroll
    for (int j = 0; j < 4; ++j){ const int q = t + 256*j; bufA[S_IDX(q)] = p[q]; }
    __syncthreads();
    fft1024<-1>(bufA, bufB, t, w);
#pragma unroll
    for (int j = 0; j < 4; ++j){ const int q = t + 256*j; p[q] = bufB[S_IDX(q)]; }
    __syncthreads();
  }
}

// Row-IDFT of (filt^T ⊙ F^T). Global slot = slot0 + blockIdx.y; scale = gslot%5, orient = gslot/5.
__global__ __launch_bounds__(256) void k_fft_inv_filter_b(const c2* __restrict__ F, c2* __restrict__ Z,
                                                          int slot0){
  const int t = threadIdx.x;
  const int gslot = slot0 + blockIdx.y;
  const int orient = gslot / 5;
  const int scale = gslot - orient*5;
  const float foinv = c_foinv[scale];
  const float cosA = c_cosA[orient], sinA = c_sinA[orient];
  __shared__ c2 bufA[1024];
  __shared__ c2 bufB[1024];
  c2 w[5]; make_tw<1>(t, w);
  for (int rr = 0; rr < 4; ++rr){
    const int row = blockIdx.x * 4 + rr;      // kx
    const c2* src = F + (size_t)row * 1024;
    c2* dst = Z + (size_t)blockIdx.y * 1048576 + (size_t)row * 1024;
    const float xx = (float)(row < 512 ? row : row - 1024) * (1.0f/1024.0f);
#pragma unroll
    for (int j = 0; j < 4; ++j){
      const int q = t + 256*j;
      const c2 v = src[q];
      const float f = filt_eval(q, row, xx, cosA, sinA, foinv);
      bufA[S_IDX(q)] = make_float2(v.x*f, v.y*f);
    }
    __syncthreads();
    fft1024<1>(bufA, bufB, t, w);
#pragma unroll
    for (int j = 0; j < 4; ++j){ const int q = t + 256*j; dst[q] = bufB[S_IDX(q)]; }
    __syncthreads();
  }
}

// In-place row-IDFT, slot = blockIdx.y.
__global__ __launch_bounds__(256) void k_fft_inv_ip(c2* __restrict__ Z){
  const int t = threadIdx.x;
  c2* base = Z + (size_t)blockIdx.y * 1048576;
  __shared__ c2 bufA[1024];
  __shared__ c2 bufB[1024];
  c2 w[5]; make_tw<1>(t, w);
  for (int rr = 0; rr < 4; ++rr){
    const int row = blockIdx.x * 4 + rr;
    c2* p = base + (size_t)row * 1024;
#pragma unroll
    for (int j = 0; j < 4; ++j){ const int q = t + 256*j; bufA[S_IDX(q)] = p[q]; }
    __syncthreads();
    fft1024<1>(bufA, bufB, t, w);
#pragma unroll
    for (int j = 0; j < 4; ++j){ const int q = t + 256*j; p[q] = bufB[S_IDX(q)]; }
    __syncthreads();
  }
}

// In-place tiled transpose: blockIdx.x = triangular pair index, blockIdx.y = slot.
__global__ void k_transpose_ip(c2* __restrict__ Zb){
  __shared__ c2 A[32][33];
  __shared__ c2 B[32][33];
  c2* base = Zb + (size_t)blockIdx.y * 1048576;
  const int p = blockIdx.x;
  int i = (int)floorf((sqrtf(8.0f*(float)p + 1.0f) - 1.0f) * 0.5f);
  while ((i+1)*(i+2)/2 <= p) ++i;
  while (i*(i+1)/2 > p) --i;
  const int j = p - i*(i+1)/2;
  const int tx = threadIdx.x, ty = threadIdx.y;
  const int r0 = i*32, c0 = j*32;
#pragma unroll
  for (int jj = 0; jj < 32; jj += 8)
    A[ty+jj][tx] = base[(size_t)(r0+ty+jj)*1024 + c0+tx];
  if (i != j){
#pragma unroll
    for (int jj = 0; jj < 32; jj += 8)
      B[ty+jj][tx] = base[(size_t)(c0+ty+jj)*1024 + r0+tx];
  }
  __syncthreads();
#pragma unroll
  for (int jj = 0; jj < 32; jj += 8)
    base[(size_t)(c0+ty+jj)*1024 + r0+tx] = A[tx][ty+jj];
  if (i != j){
#pragma unroll
    for (int jj = 0; jj < 32; jj += 8)
      base[(size_t)(r0+ty+jj)*1024 + c0+tx] = B[tx][ty+jj];
  }
}

// ---------------- exact median via 3-level radix select (12/12/8 bits) ----------

__device__ __forceinline__ unsigned amp_bits(const c2 v){
  return __float_as_uint(sqrtf(v.x*v.x + v.y*v.y));
}

__global__ __launch_bounds__(256) void k_med_p1b(const c2* __restrict__ Zb, size_t oStride,
                                                 unsigned* __restrict__ g1, int oBase){
  __shared__ unsigned h[4][4096];
  const int t = threadIdx.x;
  const int wv = t >> 6;
  const c2* z0 = Zb + (size_t)blockIdx.y * oStride;
  unsigned* gg = g1 + (size_t)(oBase + blockIdx.y) * 4096;
  for (int j = t; j < 4*4096; j += 256) ((unsigned*)h)[j] = 0;
  __syncthreads();
  const int base = blockIdx.x * 16384;
  for (int it = 0; it < 64; ++it){
    const unsigned bits = amp_bits(z0[base + it*256 + t]);
    atomicAdd(&h[wv][bits >> 20], 1u);
  }
  __syncthreads();
  for (int j = t; j < 4096; j += 256){
    const unsigned s = h[0][j] + h[1][j] + h[2][j] + h[3][j];
    if (s) atomicAdd(&gg[j], s);
  }
}

__global__ __launch_bounds__(256) void k_sel1b(const unsigned* __restrict__ g1,
                                               unsigned* __restrict__ sc1,
                                               unsigned* __restrict__ g2, int oBase){
  __shared__ unsigned partial[256];
  const int t = threadIdx.x;
  const int oo = oBase + blockIdx.x;
  const unsigned* gg = g1 + (size_t)oo * 4096;
  unsigned loc[16]; unsigned s = 0;
#pragma unroll
  for (int j = 0; j < 16; ++j){ loc[j] = gg[t*16 + j]; s += loc[j]; }
  partial[t] = s;
  __syncthreads();
  unsigned p = 0;
  for (int u = 0; u < t; ++u) p += partial[u];
  for (int which = 0; which < 2; ++which){
    const unsigned R = 524287u + (unsigned)which;
    if (R >= p && R - p < s){
      unsigned cum = p;
      for (int j = 0; j < 16; ++j){
        if (R - cum < loc[j]){ sc1[oo*4 + which*2] = (unsigned)(t*16 + j); sc1[oo*4 + which*2+1] = R - cum; break; }
        cum += loc[j];
      }
    }
  }
  for (int j = t; j < 8192; j += 256) g2[(size_t)oo*8192 + j] = 0;
}

__global__ __launch_bounds__(256) void k_med_p2b(const c2* __restrict__ Zb, size_t oStride,
                                                 const unsigned* __restrict__ sc1,
                                                 unsigned* __restrict__ g2, int oBase){
  __shared__ unsigned h[2][4096];
  const int t = threadIdx.x;
  const int oo = oBase + blockIdx.y;
  const c2* z0 = Zb + (size_t)blockIdx.y * oStride;
  unsigned* gg = g2 + (size_t)oo * 8192;
  for (int j = t; j < 8192; j += 256) ((unsigned*)h)[j] = 0;
  __syncthreads();
  const unsigned b0 = sc1[oo*4 + 0], b1 = sc1[oo*4 + 2];
  const int base = blockIdx.x * 16384;
  for (int it = 0; it < 64; ++it){
    const unsigned bits = amp_bits(z0[base + it*256 + t]);
    const unsigned top = bits >> 20;
    const unsigned mid = (bits >> 8) & 4095u;
    if (top == b0)      atomicAdd(&h[0][mid], 1u);
    else if (top == b1) atomicAdd(&h[1][mid], 1u);
  }
  __syncthreads();
  for (int j = t; j < 4096; j += 256){
    if (h[0][j]) atomicAdd(&gg[j], h[0][j]);
    if (h[1][j]) atomicAdd(&gg[4096 + j], h[1][j]);
  }
}

__global__ __launch_bounds__(256) void k_sel2b(const unsigned* __restrict__ g2,
                                               const unsigned* __restrict__ sc1,
                                               unsigned* __restrict__ sc2,
                                               unsigned* __restrict__ g3, int oBase){
  __shared__ unsigned partial[256];
  const int t = threadIdx.x;
  const int oo = oBase + blockIdx.x;
  const unsigned b0 = sc1[oo*4+0], lr0 = sc1[oo*4+1], b1 = sc1[oo*4+2], lr1 = sc1[oo*4+3];
  for (int which = 0; which < 2; ++which){
    const unsigned* hh = g2 + (size_t)oo*8192 + ((which == 1 && b1 != b0) ? 4096 : 0);
    const unsigned R = which ? lr1 : lr0;
    unsigned loc[16]; unsigned s = 0;
#pragma unroll
    for (int j = 0; j < 16; ++j){ loc[j] = hh[t*16 + j]; s += loc[j]; }
    partial[t] = s;
    __syncthreads();
    unsigned p = 0;
    for (int u = 0; u < t; ++u) p += partial[u];
    if (R >= p && R - p < s){
      unsigned cum = p;
      for (int j = 0; j < 16; ++j){
        if (R - cum < loc[j]){ sc2[oo*4 + which*2] = (unsigned)(t*16 + j); sc2[oo*4 + which*2+1] = R - cum; break; }
        cum += loc[j];
      }
    }
    __syncthreads();
  }
  for (int j = t; j < 512; j += 256) g3[(size_t)oo*512 + j] = 0;
}

__global__ __launch_bounds__(256) void k_med_p3b(const c2* __restrict__ Zb, size_t oStride,
                                                 const unsigned* __restrict__ sc1,
                                                 const unsigned* __restrict__ sc2,
                                                 unsigned* __restrict__ g3, int oBase){
  __shared__ unsigned h[2][256];
  const int t = threadIdx.x;
  const int oo = oBase + blockIdx.y;
  const c2* z0 = Zb + (size_t)blockIdx.y * oStride;
  unsigned* gg = g3 + (size_t)oo * 512;
  h[0][t] = 0; h[1][t] = 0;
  __syncthreads();
  const unsigned k0 = (sc1[oo*4+0] << 12) | sc2[oo*4+0];
  const unsigned k1 = (sc1[oo*4+2] << 12) | sc2[oo*4+2];
  const int base = blockIdx.x * 16384;
  for (int it = 0; it < 64; ++it){
    const unsigned bits = amp_bits(z0[base + it*256 + t]);
    const unsigned key = bits >> 8;
    if (key == k0)       atomicAdd(&h[0][bits & 255u], 1u);
    else if (key == k1)  atomicAdd(&h[1][bits & 255u], 1u);
  }
  __syncthreads();
  if (h[0][t]) atomicAdd(&gg[t], h[0][t]);
  if (h[1][t]) atomicAdd(&gg[256 + t], h[1][t]);
}

__global__ __launch_bounds__(256) void k_sel3b(const unsigned* __restrict__ g3,
                                               const unsigned* __restrict__ sc1,
                                               const unsigned* __restrict__ sc2,
                                               float* __restrict__ Tval, int oBase){
  __shared__ unsigned partial[256];
  __shared__ float vres[2];
  const int t = threadIdx.x;
  const int oo = oBase + blockIdx.x;
  const unsigned k0 = (sc1[oo*4+0] << 12) | sc2[oo*4+0];
  const unsigned k1 = (sc1[oo*4+2] << 12) | sc2[oo*4+2];
  for (int which = 0; which < 2; ++which){
    const unsigned* hh = g3 + (size_t)oo*512 + ((which == 1 && k1 != k0) ? 256 : 0);
    const unsigned R = which ? sc2[oo*4+3] : sc2[oo*4+1];
    partial[t] = hh[t];
    __syncthreads();
    unsigned p = 0;
    for (int u = 0; u < t; ++u) p += partial[u];
    if (R >= p && R - p < partial[t]){
      const unsigned key = which ? k1 : k0;
      vres[which] = __uint_as_float((key << 8) | (unsigned)t);
    }
    __syncthreads();
  }
  if (t == 0){
    const float med = 0.5f * (vres[0] + vres[1]);
    const float tau = med / 1.17741001f;              // sqrt(ln 4)
    const float totalTau = tau * 1.8623464f;          // (1-(1/2.1)^5)/(1-1/2.1)
    const float T = totalTau * 1.25331414f + 2.0f * totalTau * 0.65513638f;
    Tval[oo] = T;
  }
}

// ---------------- fused per-pixel: all 6 orientations + final M,m ----------------

__global__ __launch_bounds__(256) void k_pix_all(const c2* __restrict__ Z, const float* __restrict__ Tval,
                                                 float* __restrict__ out){
  const int i = blockIdx.x * 256 + threadIdx.x;
  float covx2 = 0.f, covy2 = 0.f, covxy = 0.f;
#pragma unroll
  for (int o = 0; o < 6; ++o){
    const float T = Tval[o];
    float E[5], O[5];
    float sumE = 0.f, sumO = 0.f, sumAn = 0.f, maxAn = 0.f;
#pragma unroll
    for (int s = 0; s < 5; ++s){
      const c2 z = Z[(size_t)(o*5 + s) * 1048576 + i];
      O[s] = z.x; E[s] = z.y;
      const float an = sqrtf(z.x*z.x + z.y*z.y);
      sumE += E[s]; sumO += O[s]; sumAn += an; maxAn = fmaxf(maxAn, an);
    }
    const float XE = sqrtf(sumE*sumE + sumO*sumO) + 1e-4f;
    const float ME = sumE / XE, MO = sumO / XE;
    float energy = 0.f;
#pragma unroll
    for (int s = 0; s < 5; ++s)
      energy += E[s]*ME + O[s]*MO - fabsf(E[s]*MO - O[s]*ME);
    energy = fmaxf(energy - T, 0.f);
    const float width = (sumAn / (maxAn + 1e-4f) - 1.0f) * 0.25f;
    const float weight = 1.0f / (1.0f + expf((0.5f - width) * 10.0f));
    const float PC = weight * energy / sumAn;
    const float cx = PC * c_cosA[o], cy = PC * c_sinA[o];
    covx2 += cx*cx; covy2 += cy*cy; covxy += cx*cy;
  }
  covx2 *= (1.0f/3.0f);
  covy2 *= (1.0f/3.0f);
  covxy *= (4.0f/6.0f);
  const float dnm = sqrtf(covxy*covxy + (covx2 - covy2)*(covx2 - covy2)) + 1e-4f;
  const float ss = covy2 + covx2;
  out[i] = (ss + dnm) / 2.0f;
  out[1048576 + i] = (ss - dnm) / 2.0f;
}

// ---------------- fallback per-orientation pixel kernels ----------------

__global__ __launch_bounds__(256) void k_pix(const c2* __restrict__ Z, const float* __restrict__ Tp,
                                             float cA, float sA,
                                             float* __restrict__ ax2, float* __restrict__ ay2,
                                             float* __restrict__ axy, int first){
  const int i = blockIdx.x * 256 + threadIdx.x;
  const float T = *Tp;
  float E[5], O[5];
  float sumE = 0.f, sumO = 0.f, sumAn = 0.f, maxAn = 0.f;
#pragma unroll
  for (int s = 0; s < 5; ++s){
    const c2 z = Z[(size_t)s * 1048576 + i];
    O[s] = z.x; E[s] = z.y;
    const float an = sqrtf(z.x*z.x + z.y*z.y);
    sumE += E[s]; sumO += O[s]; sumAn += an; maxAn = fmaxf(maxAn, an);
  }
  const float XE = sqrtf(sumE*sumE + sumO*sumO) + 1e-4f;
  const float ME = sumE / XE, MO = sumO / XE;
  float energy = 0.f;
#pragma unroll
  for (int s = 0; s < 5; ++s)
    energy += E[s]*ME + O[s]*MO - fabsf(E[s]*MO - O[s]*ME);
  energy = fmaxf(energy - T, 0.f);
  const float width = (sumAn / (maxAn + 1e-4f) - 1.0f) * 0.25f;
  const float weight = 1.0f / (1.0f + expf((0.5f - width) * 10.0f));
  const float PC = weight * energy / sumAn;
  const float cx = PC * cA, cy = PC * sA;
  if (first){ ax2[i] = cx*cx; ay2[i] = cy*cy; axy[i] = cx*cy; }
  else      { ax2[i] += cx*cx; ay2[i] += cy*cy; axy[i] += cx*cy; }
}

__global__ __launch_bounds__(256) void k_final(const float* __restrict__ ax2, const float* __restrict__ ay2,
                                               const float* __restrict__ axy, float* __restrict__ out){
  const int i = blockIdx.x * 256 + threadIdx.x;
  const float cx2 = ax2[i] / 3.0f;
  const float cy2 = ay2[i] / 3.0f;
  const float cxy = 4.0f * axy[i] / 6.0f;
  const float dnm = sqrtf(cxy*cxy + (cx2 - cy2)*(cx2 - cy2)) + 1e-4f;
  const float ss = cy2 + cx2;
  out[i] = (ss + dnm) / 2.0f;
  out[1048576 + i] = (ss - dnm) / 2.0f;
}

extern "C" void kernel_launch(void* const* d_in, const int* in_sizes, int n_in,
                              void* d_out, int out_size, void* d_ws, size_t ws_size,
                              hipStream_t stream){
  (void)in_sizes; (void)n_in; (void)out_size;
  const float* img = (const float*)d_in[0];
  float* out = (float*)d_out;
  char* w = (char*)d_ws;

  const dim3 th(256);
  const dim3 thT(32, 8);

  if (ws_size >= (size_t)260360000){
    // -------- full-batch path: F (8 MB) + 30 Z planes (240 MB) + scratch --------
    c2* F  = (c2*)(w);
    c2* Z  = (c2*)(w + 8388608);
    unsigned* g1  = (unsigned*)(w + 260046848);
    unsigned* g2  = (unsigned*)(w + 260145152);
    unsigned* g3  = (unsigned*)(w + 260341760);
    unsigned* sc1 = (unsigned*)(w + 260354048);
    unsigned* sc2 = (unsigned*)(w + 260354176);
    float* Tval   = (float*)(w + 260354304);

    // forward: rowFFT(img) -> F ; transpose in place ; rowFFT in place  => F^T
    k_fft_fwd_real<<<dim3(256), th, 0, stream>>>(img, F);
    k_transpose_ip<<<dim3(528, 1), thT, 0, stream>>>(F);
    k_fft_fwd_ip<<<dim3(256, 1), th, 0, stream>>>(F);

    // all 30 channels: filter + col-IFFT, in-place transpose, row-IFFT
    k_fft_inv_filter_b<<<dim3(256, 30), th, 0, stream>>>(F, Z, 0);
    k_transpose_ip<<<dim3(528, 30), thT, 0, stream>>>(Z);
    k_fft_inv_ip<<<dim3(256, 30), th, 0, stream>>>(Z);

    // medians for 6 orientations (scale-0 planes), batched
    hipMemsetAsync(g1, 0, 6*16384, stream);
    const size_t oStride = (size_t)5 * 1048576;
    k_med_p1b<<<dim3(64, 6), th, 0, stream>>>(Z, oStride, g1, 0);
    k_sel1b<<<dim3(6), th, 0, stream>>>(g1, sc1, g2, 0);
    k_med_p2b<<<dim3(64, 6), th, 0, stream>>>(Z, oStride, sc1, g2, 0);
    k_sel2b<<<dim3(6), th, 0, stream>>>(g2, sc1, sc2, g3, 0);
    k_med_p3b<<<dim3(64, 6), th, 0, stream>>>(Z, oStride, sc1, sc2, g3, 0);
    k_sel3b<<<dim3(6), th, 0, stream>>>(g3, sc1, sc2, Tval, 0);

    // fused per-pixel PC + covariance + M,m
    k_pix_all<<<dim3(4096), th, 0, stream>>>(Z, Tval, out);
  } else {
    // -------- fallback: per-orientation (needs ~63 MB) --------
    c2* F   = (c2*)(w);
    c2* C5  = (c2*)(w + 8388608);                 // 5 planes, 40 MB
    float* ax2 = (float*)(w + 50331648);
    float* ay2 = ax2 + 1048576;
    float* axy = ay2 + 1048576;
    unsigned* g1  = (unsigned*)(w + 62914560);
    unsigned* g2  = (unsigned*)(w + 62930944);
    unsigned* g3  = (unsigned*)(w + 62963712);
    unsigned* sc1 = (unsigned*)(w + 62965760);
    unsigned* sc2 = (unsigned*)(w + 62965888);
    float* Tval   = (float*)(w + 62966016);

    k_fft_fwd_real<<<dim3(256), th, 0, stream>>>(img, F);
    k_transpose_ip<<<dim3(528, 1), thT, 0, stream>>>(F);
    k_fft_fwd_ip<<<dim3(256, 1), th, 0, stream>>>(F);

    for (int o = 0; o < 6; ++o){
      k_fft_inv_filter_b<<<dim3(256, 5), th, 0, stream>>>(F, C5, o*5);
      k_transpose_ip<<<dim3(528, 5), thT, 0, stream>>>(C5);
      k_fft_inv_ip<<<dim3(256, 5), th, 0, stream>>>(C5);

      hipMemsetAsync(g1, 0, 16384, stream);
      k_med_p1b<<<dim3(64, 1), th, 0, stream>>>(C5, 0, g1, 0);
      k_sel1b<<<dim3(1), th, 0, stream>>>(g1, sc1, g2, 0);
      k_med_p2b<<<dim3(64, 1), th, 0, stream>>>(C5, 0, sc1, g2, 0);
      k_sel2b<<<dim3(1), th, 0, stream>>>(g2, sc1, sc2, g3, 0);
      k_med_p3b<<<dim3(64, 1), th, 0, stream>>>(C5, 0, sc1, sc2, g3, 0);
      k_sel3b<<<dim3(1), th, 0, stream>>>(g3, sc1, sc2, Tval, 0);

      const double a = (double)o * (M_PI/6.0);
      k_pix<<<dim3(4096), th, 0, stream>>>(C5, Tval, (float)cos(a), (float)sin(a),
                                           ax2, ay2, axy, (o == 0) ? 1 : 0);
    }
    k_final<<<dim3(4096), th, 0, stream>>>(ax2, ay2, axy, out);
  }
}

// Round 5
// 420.898 us; speedup vs baseline: 10.1618x; 1.1546x over previous
//
#include <hip/hip_runtime.h>
#include <math.h>

typedef float2 c2;

#define S_IDX(i) ((i) ^ (((i) >> 5) & 15))

__device__ __forceinline__ c2 cmul(c2 a, c2 b){
  return make_float2(a.x*b.x - a.y*b.y, a.x*b.y + a.y*b.x);
}

__constant__ float c_foinv[5] = {3.0f, 6.3f, 13.23f, 27.783f, 58.3443f};
__constant__ float c_lnfo[5]  = {1.0986123f, 1.8405496f, 2.5824700f, 3.3244106f, 4.0663219f};
__constant__ float c_angl[6]  = {0.0f, 0.5235988f, 1.0471976f, 1.5707963f, 2.0943951f, 2.6179939f};
__constant__ float c_cosA[6] = {1.0f, 0.8660254038f, 0.5f, 6.123233996e-17f, -0.5f, -0.8660254038f};
__constant__ float c_sinA[6] = {0.0f, 0.5f, 0.8660254038f, 1.0f, 0.8660254038f, 0.5f};

template<int SIGN>
__device__ __forceinline__ void make_tw(int t, c2* w){
#pragma unroll
  for (int k = 0; k < 5; ++k){
    const int s = 1 << (2*k);
    const float ang = (float)SIGN * 0.00613592315154256f * (float)(t & ~(s-1));
    sincosf(ang, &w[k].y, &w[k].x);
  }
}

// Radix-4 Stockham, N=1024, 256 threads, result ends in bufB, natural order.
template<int SIGN>
__device__ __forceinline__ void fft1024(c2* bufA, c2* bufB, int t, const c2* w){
  c2* cur = bufA; c2* oth = bufB;
#pragma unroll
  for (int k = 0; k < 5; ++k){
    const int s = 1 << (2*k);
    const int q = t & (s - 1);
    c2 a = cur[S_IDX(t)];
    c2 b = cur[S_IDX(t + 256)];
    c2 c = cur[S_IDX(t + 512)];
    c2 d = cur[S_IDX(t + 768)];
    c2 w1 = w[k];
    c2 w2 = cmul(w1, w1);
    c2 w3 = cmul(w2, w1);
    c2 apc = make_float2(a.x + c.x, a.y + c.y);
    c2 amc = make_float2(a.x - c.x, a.y - c.y);
    c2 bpd = make_float2(b.x + d.x, b.y + d.y);
    c2 bmd = make_float2(b.x - d.x, b.y - d.y);
    c2 y0 = make_float2(apc.x + bpd.x, apc.y + bpd.y);
    c2 e2 = make_float2(apc.x - bpd.x, apc.y - bpd.y);
    const float S4 = (float)SIGN;
    c2 u1 = make_float2(amc.x - S4*bmd.y, amc.y + S4*bmd.x);
    c2 u3 = make_float2(amc.x + S4*bmd.y, amc.y - S4*bmd.x);
    c2 y1 = cmul(u1, w1);
    c2 y2 = cmul(e2, w2);
    c2 y3 = cmul(u3, w3);
    const int bw = 4*t - 3*q;
    oth[S_IDX(bw)]       = y0;
    oth[S_IDX(bw + s)]   = y1;
    oth[S_IDX(bw + 2*s)] = y2;
    oth[S_IDX(bw + 3*s)] = y3;
    c2* tmp = cur; cur = oth; oth = tmp;
    __syncthreads();
  }
}

// Log-Gabor * lowpass * angular spread at DFT coords (r=q, c=a) -- analytic (fallback path)
__device__ __forceinline__ float filt_eval(int q, int a, float xx,
                                           float cosA, float sinA, float foinv){
  const float yy = (float)(q < 512 ? q : q - 1024) * (1.0f/1024.0f);
  const float r2 = xx*xx + yy*yy;
  const bool isdc = (q == 0) && (a == 0);
  const float radius = isdc ? 1.0f : sqrtf(r2);
  const float tt = radius * (1.0f/0.45f);
  const float t2 = tt*tt, t4 = t2*t2, t8 = t4*t4, t16 = t8*t8;
  const float lp = 1.0f / (1.0f + t16*t8*t4*t2);
  const float lnr = logf(radius * foinv);
  const float lg = expf(-lnr*lnr * 1.3989572f);   // 1/(2*ln(0.55)^2)
  const float ir = 1.0f / radius;
  const float st = -yy * ir, ct = xx * ir;
  const float dsv = st*cosA - ct*sinA;
  const float dcv = ct*cosA + st*sinA;
  const float dth = fminf(fabsf(atan2f(dsv, dcv)) * 3.0f, 3.14159274f);
  const float spr = 0.5f * (cosf(dth) + 1.0f);
  const float f = lg * lp * spr;
  return isdc ? 0.0f : f;
}

// Precompute per-pixel invariants in F^T layout: lnr = ln(radius), theta = atan2(-yy, xx).
// Row a = x-frequency, col q = y-frequency (matches k_fft_inv_filter row/col roles).
__global__ __launch_bounds__(256) void k_filt_tab(float* __restrict__ lnrT, float* __restrict__ thetaT){
  const int a = blockIdx.x;
  const int t = threadIdx.x;
  const float xx = (float)(a < 512 ? a : a - 1024) * (1.0f/1024.0f);
#pragma unroll
  for (int j = 0; j < 4; ++j){
    const int q = t + 256*j;
    const float yy = (float)(q < 512 ? q : q - 1024) * (1.0f/1024.0f);
    const float radius = sqrtf(xx*xx + yy*yy);
    float lnr = logf(radius);
    if (a == 0 && q == 0) lnr = __int_as_float(0x7F800000);  // +inf -> filter 0 at DC
    const float th = atan2f(-yy, xx);
    lnrT[a*1024 + q] = lnr;
    thetaT[a*1024 + q] = th;
  }
}

__global__ __launch_bounds__(256) void k_fft_fwd_real(const float* __restrict__ in, c2* __restrict__ out){
  const int t = threadIdx.x;
  __shared__ c2 bufA[1024];
  __shared__ c2 bufB[1024];
  c2 w[5]; make_tw<-1>(t, w);
  for (int rr = 0; rr < 4; ++rr){
    const int row = blockIdx.x * 4 + rr;
    const float* src = in + (size_t)row * 1024;
    c2* dst = out + (size_t)row * 1024;
#pragma unroll
    for (int j = 0; j < 4; ++j){
      const int q = t + 256*j;
      bufA[S_IDX(q)] = make_float2(src[q], 0.0f);
    }
    __syncthreads();
    fft1024<-1>(bufA, bufB, t, w);
#pragma unroll
    for (int j = 0; j < 4; ++j){ const int q = t + 256*j; dst[q] = bufB[S_IDX(q)]; }
    __syncthreads();
  }
}

// In-place row-FFT (forward), slot = blockIdx.y
__global__ __launch_bounds__(256) void k_fft_fwd_ip(c2* __restrict__ Z){
  const int t = threadIdx.x;
  c2* base = Z + (size_t)blockIdx.y * 1048576;
  __shared__ c2 bufA[1024];
  __shared__ c2 bufB[1024];
  c2 w[5]; make_tw<-1>(t, w);
  for (int rr = 0; rr < 4; ++rr){
    const int row = blockIdx.x * 4 + rr;
    c2* p = base + (size_t)row * 1024;
#pragma unroll
    for (int j = 0; j < 4; ++j){ const int q = t + 256*j; bufA[S_IDX(q)] = p[q]; }
    __syncthreads();
    fft1024<-1>(bufA, bufB, t, w);
#pragma unroll
    for (int j = 0; j < 4; ++j){ const int q = t + 256*j; p[q] = bufB[S_IDX(q)]; }
    __syncthreads();
  }
}

// Table-based row-IDFT of (filt^T ⊙ F^T).  slot = blockIdx.y; scale = slot%5, orient = slot/5.
__global__ __launch_bounds__(256) void k_fft_inv_filter_t(const c2* __restrict__ F, c2* __restrict__ Z,
                                                          const float* __restrict__ lnrT,
                                                          const float* __restrict__ thetaT){
  const int t = threadIdx.x;
  const int gslot = blockIdx.y;
  const int orient = gslot / 5;
  const int scale = gslot - orient*5;
  const float lnfo = c_lnfo[scale];
  const float angl = c_angl[orient];
  __shared__ c2 bufA[1024];
  __shared__ c2 bufB[1024];
  c2 w[5]; make_tw<1>(t, w);
  for (int rr = 0; rr < 4; ++rr){
    const int row = blockIdx.x * 4 + rr;
    const c2* src = F + (size_t)row * 1024;
    const float* lnrR = lnrT + (size_t)row * 1024;
    const float* thR  = thetaT + (size_t)row * 1024;
    c2* dst = Z + (size_t)gslot * 1048576 + (size_t)row * 1024;
#pragma unroll
    for (int j = 0; j < 4; ++j){
      const int q = t + 256*j;
      const c2 v = src[q];
      const float lnr = lnrR[q];
      const float th  = thR[q];
      // radial: logGabor
      const float u = lnr + lnfo;
      const float lg = __expf(-u*u * 1.3989572f);
      // lowpass Butterworth: 1/(1+(r/0.45)^30) = 1/(1+exp(30*lnr - 30*ln0.45))
      const float lp = 1.0f / (1.0f + __expf(fmaf(30.0f, lnr, 23.955231f)));
      // angular spread: |wrap(theta - angl)|
      float d = th - angl;
      if (d <= -3.14159274f) d += 6.28318548f;
      const float dth = fminf(fabsf(d) * 3.0f, 3.14159274f);
      const float spr = 0.5f * (__cosf(dth) + 1.0f);
      const float f = lg * lp * spr;
      bufA[S_IDX(q)] = make_float2(v.x*f, v.y*f);
    }
    __syncthreads();
    fft1024<1>(bufA, bufB, t, w);
#pragma unroll
    for (int j = 0; j < 4; ++j){ const int q = t + 256*j; dst[q] = bufB[S_IDX(q)]; }
    __syncthreads();
  }
}

// Analytic variant (fallback path). slot0 + blockIdx.y selects (orient,scale).
__global__ __launch_bounds__(256) void k_fft_inv_filter_b(const c2* __restrict__ F, c2* __restrict__ Z,
                                                          int slot0){
  const int t = threadIdx.x;
  const int gslot = slot0 + blockIdx.y;
  const int orient = gslot / 5;
  const int scale = gslot - orient*5;
  const float foinv = c_foinv[scale];
  const float cosA = c_cosA[orient], sinA = c_sinA[orient];
  __shared__ c2 bufA[1024];
  __shared__ c2 bufB[1024];
  c2 w[5]; make_tw<1>(t, w);
  for (int rr = 0; rr < 4; ++rr){
    const int row = blockIdx.x * 4 + rr;
    const c2* src = F + (size_t)row * 1024;
    c2* dst = Z + (size_t)blockIdx.y * 1048576 + (size_t)row * 1024;
    const float xx = (float)(row < 512 ? row : row - 1024) * (1.0f/1024.0f);
#pragma unroll
    for (int j = 0; j < 4; ++j){
      const int q = t + 256*j;
      const c2 v = src[q];
      const float f = filt_eval(q, row, xx, cosA, sinA, foinv);
      bufA[S_IDX(q)] = make_float2(v.x*f, v.y*f);
    }
    __syncthreads();
    fft1024<1>(bufA, bufB, t, w);
#pragma unroll
    for (int j = 0; j < 4; ++j){ const int q = t + 256*j; dst[q] = bufB[S_IDX(q)]; }
    __syncthreads();
  }
}

// In-place row-IDFT, slot = blockIdx.y.
__global__ __launch_bounds__(256) void k_fft_inv_ip(c2* __restrict__ Z){
  const int t = threadIdx.x;
  c2* base = Z + (size_t)blockIdx.y * 1048576;
  __shared__ c2 bufA[1024];
  __shared__ c2 bufB[1024];
  c2 w[5]; make_tw<1>(t, w);
  for (int rr = 0; rr < 4; ++rr){
    const int row = blockIdx.x * 4 + rr;
    c2* p = base + (size_t)row * 1024;
#pragma unroll
    for (int j = 0; j < 4; ++j){ const int q = t + 256*j; bufA[S_IDX(q)] = p[q]; }
    __syncthreads();
    fft1024<1>(bufA, bufB, t, w);
#pragma unroll
    for (int j = 0; j < 4; ++j){ const int q = t + 256*j; p[q] = bufB[S_IDX(q)]; }
    __syncthreads();
  }
}

// In-place tiled transpose: blockIdx.x = triangular pair index, blockIdx.y = slot.
__global__ void k_transpose_ip(c2* __restrict__ Zb){
  __shared__ c2 A[32][33];
  __shared__ c2 B[32][33];
  c2* base = Zb + (size_t)blockIdx.y * 1048576;
  const int p = blockIdx.x;
  int i = (int)floorf((sqrtf(8.0f*(float)p + 1.0f) - 1.0f) * 0.5f);
  while ((i+1)*(i+2)/2 <= p) ++i;
  while (i*(i+1)/2 > p) --i;
  const int j = p - i*(i+1)/2;
  const int tx = threadIdx.x, ty = threadIdx.y;
  const int r0 = i*32, c0 = j*32;
#pragma unroll
  for (int jj = 0; jj < 32; jj += 8)
    A[ty+jj][tx] = base[(size_t)(r0+ty+jj)*1024 + c0+tx];
  if (i != j){
#pragma unroll
    for (int jj = 0; jj < 32; jj += 8)
      B[ty+jj][tx] = base[(size_t)(c0+ty+jj)*1024 + r0+tx];
  }
  __syncthreads();
#pragma unroll
  for (int jj = 0; jj < 32; jj += 8)
    base[(size_t)(c0+ty+jj)*1024 + r0+tx] = A[tx][ty+jj];
  if (i != j){
#pragma unroll
    for (int jj = 0; jj < 32; jj += 8)
      base[(size_t)(r0+ty+jj)*1024 + c0+tx] = B[tx][ty+jj];
  }
}

// ---------------- exact median via 3-level radix select (12/12/8 bits) ----------

__device__ __forceinline__ unsigned amp_bits(const c2 v){
  return __float_as_uint(sqrtf(v.x*v.x + v.y*v.y));
}

__global__ __launch_bounds__(256) void k_med_p1b(const c2* __restrict__ Zb, size_t oStride,
                                                 unsigned* __restrict__ g1, int oBase){
  __shared__ unsigned h[4][4096];
  const int t = threadIdx.x;
  const int wv = t >> 6;
  const c2* z0 = Zb + (size_t)blockIdx.y * oStride;
  unsigned* gg = g1 + (size_t)(oBase + blockIdx.y) * 4096;
  for (int j = t; j < 4*4096; j += 256) ((unsigned*)h)[j] = 0;
  __syncthreads();
  const int base = blockIdx.x * 16384;
  for (int it = 0; it < 64; ++it){
    const unsigned bits = amp_bits(z0[base + it*256 + t]);
    atomicAdd(&h[wv][bits >> 20], 1u);
  }
  __syncthreads();
  for (int j = t; j < 4096; j += 256){
    const unsigned s = h[0][j] + h[1][j] + h[2][j] + h[3][j];
    if (s) atomicAdd(&gg[j], s);
  }
}

__global__ __launch_bounds__(256) void k_sel1b(const unsigned* __restrict__ g1,
                                               unsigned* __restrict__ sc1,
                                               unsigned* __restrict__ g2, int oBase){
  __shared__ unsigned partial[256];
  const int t = threadIdx.x;
  const int oo = oBase + blockIdx.x;
  const unsigned* gg = g1 + (size_t)oo * 4096;
  unsigned loc[16]; unsigned s = 0;
#pragma unroll
  for (int j = 0; j < 16; ++j){ loc[j] = gg[t*16 + j]; s += loc[j]; }
  partial[t] = s;
  __syncthreads();
  unsigned p = 0;
  for (int u = 0; u < t; ++u) p += partial[u];
  for (int which = 0; which < 2; ++which){
    const unsigned R = 524287u + (unsigned)which;
    if (R >= p && R - p < s){
      unsigned cum = p;
      for (int j = 0; j < 16; ++j){
        if (R - cum < loc[j]){ sc1[oo*4 + which*2] = (unsigned)(t*16 + j); sc1[oo*4 + which*2+1] = R - cum; break; }
        cum += loc[j];
      }
    }
  }
  for (int j = t; j < 8192; j += 256) g2[(size_t)oo*8192 + j] = 0;
}

__global__ __launch_bounds__(256) void k_med_p2b(const c2* __restrict__ Zb, size_t oStride,
                                                 const unsigned* __restrict__ sc1,
                                                 unsigned* __restrict__ g2, int oBase){
  __shared__ unsigned h[2][4096];
  const int t = threadIdx.x;
  const int oo = oBase + blockIdx.y;
  const c2* z0 = Zb + (size_t)blockIdx.y * oStride;
  unsigned* gg = g2 + (size_t)oo * 8192;
  for (int j = t; j < 8192; j += 256) ((unsigned*)h)[j] = 0;
  __syncthreads();
  const unsigned b0 = sc1[oo*4 + 0], b1 = sc1[oo*4 + 2];
  const int base = blockIdx.x * 16384;
  for (int it = 0; it < 64; ++it){
    const unsigned bits = amp_bits(z0[base + it*256 + t]);
    const unsigned top = bits >> 20;
    const unsigned mid = (bits >> 8) & 4095u;
    if (top == b0)      atomicAdd(&h[0][mid], 1u);
    else if (top == b1) atomicAdd(&h[1][mid], 1u);
  }
  __syncthreads();
  for (int j = t; j < 4096; j += 256){
    if (h[0][j]) atomicAdd(&gg[j], h[0][j]);
    if (h[1][j]) atomicAdd(&gg[4096 + j], h[1][j]);
  }
}

__global__ __launch_bounds__(256) void k_sel2b(const unsigned* __restrict__ g2,
                                               const unsigned* __restrict__ sc1,
                                               unsigned* __restrict__ sc2,
                                               unsigned* __restrict__ g3, int oBase){
  __shared__ unsigned partial[256];
  const int t = threadIdx.x;
  const int oo = oBase + blockIdx.x;
  const unsigned b0 = sc1[oo*4+0], lr0 = sc1[oo*4+1], b1 = sc1[oo*4+2], lr1 = sc1[oo*4+3];
  for (int which = 0; which < 2; ++which){
    const unsigned* hh = g2 + (size_t)oo*8192 + ((which == 1 && b1 != b0) ? 4096 : 0);
    const unsigned R = which ? lr1 : lr0;
    unsigned loc[16]; unsigned s = 0;
#pragma unroll
    for (int j = 0; j < 16; ++j){ loc[j] = hh[t*16 + j]; s += loc[j]; }
    partial[t] = s;
    __syncthreads();
    unsigned p = 0;
    for (int u = 0; u < t; ++u) p += partial[u];
    if (R >= p && R - p < s){
      unsigned cum = p;
      for (int j = 0; j < 16; ++j){
        if (R - cum < loc[j]){ sc2[oo*4 + which*2] = (unsigned)(t*16 + j); sc2[oo*4 + which*2+1] = R - cum; break; }
        cum += loc[j];
      }
    }
    __syncthreads();
  }
  for (int j = t; j < 512; j += 256) g3[(size_t)oo*512 + j] = 0;
}

__global__ __launch_bounds__(256) void k_med_p3b(const c2* __restrict__ Zb, size_t oStride,
                                                 const unsigned* __restrict__ sc1,
                                                 const unsigned* __restrict__ sc2,
                                                 unsigned* __restrict__ g3, int oBase){
  __shared__ unsigned h[2][256];
  const int t = threadIdx.x;
  const int oo = oBase + blockIdx.y;
  const c2* z0 = Zb + (size_t)blockIdx.y * oStride;
  unsigned* gg = g3 + (size_t)oo * 512;
  h[0][t] = 0; h[1][t] = 0;
  __syncthreads();
  const unsigned k0 = (sc1[oo*4+0] << 12) | sc2[oo*4+0];
  const unsigned k1 = (sc1[oo*4+2] << 12) | sc2[oo*4+2];
  const int base = blockIdx.x * 16384;
  for (int it = 0; it < 64; ++it){
    const unsigned bits = amp_bits(z0[base + it*256 + t]);
    const unsigned key = bits >> 8;
    if (key == k0)       atomicAdd(&h[0][bits & 255u], 1u);
    else if (key == k1)  atomicAdd(&h[1][bits & 255u], 1u);
  }
  __syncthreads();
  if (h[0][t]) atomicAdd(&gg[t], h[0][t]);
  if (h[1][t]) atomicAdd(&gg[256 + t], h[1][t]);
}

__global__ __launch_bounds__(256) void k_sel3b(const unsigned* __restrict__ g3,
                                               const unsigned* __restrict__ sc1,
                                               const unsigned* __restrict__ sc2,
                                               float* __restrict__ Tval, int oBase){
  __shared__ unsigned partial[256];
  __shared__ float vres[2];
  const int t = threadIdx.x;
  const int oo = oBase + blockIdx.x;
  const unsigned k0 = (sc1[oo*4+0] << 12) | sc2[oo*4+0];
  const unsigned k1 = (sc1[oo*4+2] << 12) | sc2[oo*4+2];
  for (int which = 0; which < 2; ++which){
    const unsigned* hh = g3 + (size_t)oo*512 + ((which == 1 && k1 != k0) ? 256 : 0);
    const unsigned R = which ? sc2[oo*4+3] : sc2[oo*4+1];
    partial[t] = hh[t];
    __syncthreads();
    unsigned p = 0;
    for (int u = 0; u < t; ++u) p += partial[u];
    if (R >= p && R - p < partial[t]){
      const unsigned key = which ? k1 : k0;
      vres[which] = __uint_as_float((key << 8) | (unsigned)t);
    }
    __syncthreads();
  }
  if (t == 0){
    const float med = 0.5f * (vres[0] + vres[1]);
    const float tau = med / 1.17741001f;              // sqrt(ln 4)
    const float totalTau = tau * 1.8623464f;          // (1-(1/2.1)^5)/(1-1/2.1)
    const float T = totalTau * 1.25331414f + 2.0f * totalTau * 0.65513638f;
    Tval[oo] = T;
  }
}

// ---------------- fused per-pixel: all 6 orientations + final M,m ----------------

__global__ __launch_bounds__(256) void k_pix_all(const c2* __restrict__ Z, const float* __restrict__ Tval,
                                                 float* __restrict__ out){
  const int i = blockIdx.x * 256 + threadIdx.x;
  float covx2 = 0.f, covy2 = 0.f, covxy = 0.f;
#pragma unroll
  for (int o = 0; o < 6; ++o){
    const float T = Tval[o];
    float E[5], O[5];
    float sumE = 0.f, sumO = 0.f, sumAn = 0.f, maxAn = 0.f;
#pragma unroll
    for (int s = 0; s < 5; ++s){
      const c2 z = Z[(size_t)(o*5 + s) * 1048576 + i];
      O[s] = z.x; E[s] = z.y;
      const float an = sqrtf(z.x*z.x + z.y*z.y);
      sumE += E[s]; sumO += O[s]; sumAn += an; maxAn = fmaxf(maxAn, an);
    }
    const float XE = sqrtf(sumE*sumE + sumO*sumO) + 1e-4f;
    const float ME = sumE / XE, MO = sumO / XE;
    float energy = 0.f;
#pragma unroll
    for (int s = 0; s < 5; ++s)
      energy += E[s]*ME + O[s]*MO - fabsf(E[s]*MO - O[s]*ME);
    energy = fmaxf(energy - T, 0.f);
    const float width = (sumAn / (maxAn + 1e-4f) - 1.0f) * 0.25f;
    const float weight = 1.0f / (1.0f + expf((0.5f - width) * 10.0f));
    const float PC = weight * energy / sumAn;
    const float cx = PC * c_cosA[o], cy = PC * c_sinA[o];
    covx2 += cx*cx; covy2 += cy*cy; covxy += cx*cy;
  }
  covx2 *= (1.0f/3.0f);
  covy2 *= (1.0f/3.0f);
  covxy *= (4.0f/6.0f);
  const float dnm = sqrtf(covxy*covxy + (covx2 - covy2)*(covx2 - covy2)) + 1e-4f;
  const float ss = covy2 + covx2;
  out[i] = (ss + dnm) / 2.0f;
  out[1048576 + i] = (ss - dnm) / 2.0f;
}

// ---------------- fallback per-orientation pixel kernels ----------------

__global__ __launch_bounds__(256) void k_pix(const c2* __restrict__ Z, const float* __restrict__ Tp,
                                             float cA, float sA,
                                             float* __restrict__ ax2, float* __restrict__ ay2,
                                             float* __restrict__ axy, int first){
  const int i = blockIdx.x * 256 + threadIdx.x;
  const float T = *Tp;
  float E[5], O[5];
  float sumE = 0.f, sumO = 0.f, sumAn = 0.f, maxAn = 0.f;
#pragma unroll
  for (int s = 0; s < 5; ++s){
    const c2 z = Z[(size_t)s * 1048576 + i];
    O[s] = z.x; E[s] = z.y;
    const float an = sqrtf(z.x*z.x + z.y*z.y);
    sumE += E[s]; sumO += O[s]; sumAn += an; maxAn = fmaxf(maxAn, an);
  }
  const float XE = sqrtf(sumE*sumE + sumO*sumO) + 1e-4f;
  const float ME = sumE / XE, MO = sumO / XE;
  float energy = 0.f;
#pragma unroll
  for (int s = 0; s < 5; ++s)
    energy += E[s]*ME + O[s]*MO - fabsf(E[s]*MO - O[s]*ME);
  energy = fmaxf(energy - T, 0.f);
  const float width = (sumAn / (maxAn + 1e-4f) - 1.0f) * 0.25f;
  const float weight = 1.0f / (1.0f + expf((0.5f - width) * 10.0f));
  const float PC = weight * energy / sumAn;
  const float cx = PC * cA, cy = PC * sA;
  if (first){ ax2[i] = cx*cx; ay2[i] = cy*cy; axy[i] = cx*cy; }
  else      { ax2[i] += cx*cx; ay2[i] += cy*cy; axy[i] += cx*cy; }
}

__global__ __launch_bounds__(256) void k_final(const float* __restrict__ ax2, const float* __restrict__ ay2,
                                               const float* __restrict__ axy, float* __restrict__ out){
  const int i = blockIdx.x * 256 + threadIdx.x;
  const float cx2 = ax2[i] / 3.0f;
  const float cy2 = ay2[i] / 3.0f;
  const float cxy = 4.0f * axy[i] / 6.0f;
  const float dnm = sqrtf(cxy*cxy + (cx2 - cy2)*(cx2 - cy2)) + 1e-4f;
  const float ss = cy2 + cx2;
  out[i] = (ss + dnm) / 2.0f;
  out[1048576 + i] = (ss - dnm) / 2.0f;
}

extern "C" void kernel_launch(void* const* d_in, const int* in_sizes, int n_in,
                              void* d_out, int out_size, void* d_ws, size_t ws_size,
                              hipStream_t stream){
  (void)in_sizes; (void)n_in; (void)out_size;
  const float* img = (const float*)d_in[0];
  float* out = (float*)d_out;
  char* w = (char*)d_ws;

  const dim3 th(256);
  const dim3 thT(32, 8);

  if (ws_size >= (size_t)268435456){
    // -------- full-batch path, exactly 256 MiB --------
    // [0, 8M)      : F (forward spectrum, transposed)  -- last read by k_fft_inv_filter_t.
    //                After that, reused as median scratch (g1/g2/g3/sc1/sc2/Tval).
    // [8M, 248M)   : Z, 30 planes of 8 MB
    // [248M, 252M) : lnr table   [252M, 256M) : theta table
    c2* F  = (c2*)(w);
    c2* Z  = (c2*)(w + 8388608);
    float* lnrT   = (float*)(w + 260046848);
    float* thetaT = (float*)(w + 264241152);
    unsigned* g1  = (unsigned*)(w);             // 6*16 KB   (aliases F, used after inv_filter)
    unsigned* g2  = (unsigned*)(w + 98304);     // 6*32 KB
    unsigned* g3  = (unsigned*)(w + 294912);    // 6*2 KB
    unsigned* sc1 = (unsigned*)(w + 307200);
    unsigned* sc2 = (unsigned*)(w + 307328);
    float* Tval   = (float*)(w + 307456);

    // filter invariant tables (independent of image)
    k_filt_tab<<<dim3(1024), th, 0, stream>>>(lnrT, thetaT);

    // forward: rowFFT(img) -> F ; transpose in place ; rowFFT in place  => F^T
    k_fft_fwd_real<<<dim3(256), th, 0, stream>>>(img, F);
    k_transpose_ip<<<dim3(528, 1), thT, 0, stream>>>(F);
    k_fft_fwd_ip<<<dim3(256, 1), th, 0, stream>>>(F);

    // all 30 channels: filter + col-IFFT, in-place transpose, row-IFFT
    k_fft_inv_filter_t<<<dim3(256, 30), th, 0, stream>>>(F, Z, lnrT, thetaT);
    k_transpose_ip<<<dim3(528, 30), thT, 0, stream>>>(Z);
    k_fft_inv_ip<<<dim3(256, 30), th, 0, stream>>>(Z);

    // medians for 6 orientations (scale-0 planes), batched
    hipMemsetAsync(g1, 0, 6*16384, stream);
    const size_t oStride = (size_t)5 * 1048576;
    k_med_p1b<<<dim3(64, 6), th, 0, stream>>>(Z, oStride, g1, 0);
    k_sel1b<<<dim3(6), th, 0, stream>>>(g1, sc1, g2, 0);
    k_med_p2b<<<dim3(64, 6), th, 0, stream>>>(Z, oStride, sc1, g2, 0);
    k_sel2b<<<dim3(6), th, 0, stream>>>(g2, sc1, sc2, g3, 0);
    k_med_p3b<<<dim3(64, 6), th, 0, stream>>>(Z, oStride, sc1, sc2, g3, 0);
    k_sel3b<<<dim3(6), th, 0, stream>>>(g3, sc1, sc2, Tval, 0);

    // fused per-pixel PC + covariance + M,m
    k_pix_all<<<dim3(4096), th, 0, stream>>>(Z, Tval, out);
  } else {
    // -------- fallback: per-orientation (needs ~63 MB) --------
    c2* F   = (c2*)(w);
    c2* C5  = (c2*)(w + 8388608);                 // 5 planes, 40 MB
    float* ax2 = (float*)(w + 50331648);
    float* ay2 = ax2 + 1048576;
    float* axy = ay2 + 1048576;
    unsigned* g1  = (unsigned*)(w + 62914560);
    unsigned* g2  = (unsigned*)(w + 62930944);
    unsigned* g3  = (unsigned*)(w + 62963712);
    unsigned* sc1 = (unsigned*)(w + 62965760);
    unsigned* sc2 = (unsigned*)(w + 62965888);
    float* Tval   = (float*)(w + 62966016);

    k_fft_fwd_real<<<dim3(256), th, 0, stream>>>(img, F);
    k_transpose_ip<<<dim3(528, 1), thT, 0, stream>>>(F);
    k_fft_fwd_ip<<<dim3(256, 1), th, 0, stream>>>(F);

    for (int o = 0; o < 6; ++o){
      k_fft_inv_filter_b<<<dim3(256, 5), th, 0, stream>>>(F, C5, o*5);
      k_transpose_ip<<<dim3(528, 5), thT, 0, stream>>>(C5);
      k_fft_inv_ip<<<dim3(256, 5), th, 0, stream>>>(C5);

      hipMemsetAsync(g1, 0, 16384, stream);
      k_med_p1b<<<dim3(64, 1), th, 0, stream>>>(C5, 0, g1, 0);
      k_sel1b<<<dim3(1), th, 0, stream>>>(g1, sc1, g2, 0);
      k_med_p2b<<<dim3(64, 1), th, 0, stream>>>(C5, 0, sc1, g2, 0);
      k_sel2b<<<dim3(1), th, 0, stream>>>(g2, sc1, sc2, g3, 0);
      k_med_p3b<<<dim3(64, 1), th, 0, stream>>>(C5, 0, sc1, sc2, g3, 0);
      k_sel3b<<<dim3(1), th, 0, stream>>>(g3, sc1, sc2, Tval, 0);

      const double a = (double)o * (M_PI/6.0);
      k_pix<<<dim3(4096), th, 0, stream>>>(C5, Tval, (float)cos(a), (float)sin(a),
                                           ax2, ay2, axy, (o == 0) ? 1 : 0);
    }
    k_final<<<dim3(4096), th, 0, stream>>>(ax2, ay2, axy, out);
  }
}